// Round 6
// baseline (92.648 us; speedup 1.0000x reference)
//
#include <hip/hip_runtime.h>
#include <math.h>

// CrowdDet RetinaNet loss constants
#define POS_T 0.5f
#define NEG_T 0.4f
#define F_ALPHA 0.25f
#define SL1_BETA 0.1f
#define SENT 3.0e8f

// d_ws layout:
//   [0,24)        : 3 doubles (loss_cls, loss_reg, num_pos)
//   [512, +XB)    : X array — inner-loop SoA tiles, per batch (ntmax+1) tiles,
//                   tile = 5 float4: {lo(gt0),lo(gt1),lo(gt2),lo(gt3), areas4}
//                   lo = {g0, g1, g2+1, g3+1}; pad/sentinel tiles never win.
//   [Yoff, ...)   : Y array — epilogue data, stride 8 floats per gt:
//                   {g0, g1, g2, g3, cls, 0, 0, 0}
#define WS_X_BYTE_OFF 512

__device__ __forceinline__ float smooth_l1(float d) {
    d = fabsf(d);
    return d < SL1_BETA ? 0.5f * d * d / SL1_BETA : d - SL1_BETA;
}

__global__ void prep_gt_kernel(const float* __restrict__ gt,
                               const float* __restrict__ im_info,
                               float* __restrict__ X, float* __restrict__ Y,
                               double* __restrict__ ws,
                               int G, int Gp, int ntmax, int B) {
#pragma clang fp contract(off)
    const int i = blockIdx.x * 256 + threadIdx.x;
    if (i < 3) ws[i] = 0.0;
    const int slots = Gp + 4;                // includes one extra sentinel tile
    const int total = B * slots;
    if (i >= total) return;
    const int b = i / slots, j = i - b * slots;
    const int nv = (int)im_info[b * 6 + 5];

    float g0, g1, g2, g3, cls, area;
    if (j < nv) {
        const float* s = gt + ((size_t)b * G + j) * 5;
        g0 = s[0]; g1 = s[1]; g2 = s[2]; g3 = s[3]; cls = s[4];
        area = (g2 - g0 + 1.f) * (g3 - g1 + 1.f);   // exact ref op order
    } else {
        // Sentinel far-away box: zero intersection with any real anchor,
        // and 0*bS > bi*S can never hold once a real gt (bi>=0) is in.
        g0 = SENT; g1 = SENT; g2 = SENT + 1.f; g3 = SENT + 1.f;
        cls = 0.f; area = 4.f;
    }

    float* Xb = X + (size_t)b * (ntmax + 1) * 20;
    const int tile = j >> 2, lane = j & 3;
    float4* xt = reinterpret_cast<float4*>(Xb + (size_t)tile * 20);
    xt[lane] = make_float4(g0, g1, g2 + 1.f, g3 + 1.f);   // pre-added +1
    Xb[(size_t)tile * 20 + 16 + lane] = area;

    if (j < Gp) {
        float* y = Y + ((size_t)b * Gp + j) * 8;
        reinterpret_cast<float4*>(y)[0] = make_float4(g0, g1, g2, g3);
        y[4] = cls;
    }
}

// 1 anchor/thread; SoA GT tiles double-buffer-prefetched through registers.
__global__ __launch_bounds__(256) void retina_loss_kernel(
    const float* __restrict__ pred_cls,   // [B,A,1]
    const float* __restrict__ pred_reg,   // [B,A,4]
    const float* __restrict__ anchors,    // [A,4]
    const float* __restrict__ im_info,    // [B,6]
    const float* __restrict__ X,          // SoA tiles
    const float* __restrict__ Y,          // epilogue records
    int A, int ntmax, int Gp,
    double* __restrict__ ws)
{
#pragma clang fp contract(off)
    const int b = blockIdx.y;
    const int a_raw = blockIdx.x * 256 + threadIdx.x;
    const bool live = a_raw < A;
    const int a = min(a_raw, A - 1);      // clamp: uniform control flow
    const int nvalid = __builtin_amdgcn_readfirstlane((int)im_info[b * 6 + 5]);
    const int ntiles = (nvalid + 3) >> 2; // sentinels cover the tail
    const float* __restrict__ Xb = X + (size_t)b * (ntmax + 1) * 20;
    const float* __restrict__ Yb = Y + (size_t)b * Gp * 8;

    const float4 anc = *reinterpret_cast<const float4*>(anchors + 4 * (size_t)a);
    const float a0 = anc.x, a1 = anc.y;
    const float aw = anc.z - anc.x + 1.f;
    const float ah = anc.w - anc.y + 1.f;
    const float area_a = aw * ah;
    const float a2p = anc.z + 1.f;        // +1 pre-added (commutes with min
    const float a3p = anc.w + 1.f;        //  bit-exactly: rounding monotone)

    // Division-free IoU argmax: iou = inter/(S-inter) monotone in inter/S =>
    // iou_i > iou_j  <=>  inter_i*S_j > inter_j*S_i (S>0). Init (-1,1) makes
    // the first gt always win; strict > == first-max (jnp.argmax tie-break).
    float bi = -1.f, bS = 1.f;
    int arg = 0;

#define PROC(gq, sgv, gidx) { \
        const float iw = fminf(a2p, (gq).z) - fmaxf(a0, (gq).x); \
        const float ih = fminf(a3p, (gq).w) - fmaxf(a1, (gq).y); \
        const float inter = fmaxf(iw, 0.f) * fmaxf(ih, 0.f); \
        const float S = area_a + (sgv); \
        const bool upd = inter * bS > bi * S; \
        bi  = upd ? inter : bi; \
        bS  = upd ? S     : bS; \
        arg = upd ? (gidx) : arg; }

    // Prime tile 0; one extra sentinel tile exists so tt+1 is always loadable.
    const float4* xt = reinterpret_cast<const float4*>(Xb);
    float4 c0 = xt[0], c1 = xt[1], c2 = xt[2], c3 = xt[3], ca = xt[4];

    for (int tt = 0; tt < ntiles; ++tt) {
        const float4* nx = reinterpret_cast<const float4*>(Xb + (size_t)(tt + 1) * 20);
        const float4 n0 = nx[0], n1 = nx[1], n2 = nx[2], n3 = nx[3], na = nx[4];
        const int gbase = tt * 4;
        PROC(c0, ca.x, gbase + 0)
        PROC(c1, ca.y, gbase + 1)
        PROC(c2, ca.z, gbase + 2)
        PROC(c3, ca.w, gbase + 3)
        c0 = n0; c1 = n1; c2 = n2; c3 = n3; ca = na;
    }
#undef PROC

    float lc = 0.f, lr = 0.f;
    int fg = 0;

    if (live) {
        // ONE division, exact ref expression: inter/((area_a+area_g)-inter)
        const float max_ov = bi / (bS - bi);

        float label = 0.f;
        bool valid = true;
        if (max_ov >= POS_T) {
            label = Yb[(size_t)arg * 8 + 4];
        } else if (max_ov >= NEG_T) {
            valid = false;                 // ignore band
        }
        fg = (label > 0.f) ? 1 : 0;

        if (valid) {
            const float x = pred_cls[(size_t)b * A + a];
            const float p = 1.f / (1.f + expf(-x));
            const float l1p = log1pf(expf(-fabsf(x)));
            const float log_p  = fminf(x, 0.f) - l1p;    // log_sigmoid(x)
            const float log_np = fminf(-x, 0.f) - l1p;   // log_sigmoid(-x)
            const float pos = (label == 1.f) ? 1.f : 0.f;
            const float omp = 1.f - p;
            lc = -(F_ALPHA * pos * (omp * omp) * log_p
                   + (1.f - F_ALPHA) * (1.f - pos) * (p * p) * log_np);
        }

        if (fg) {
            const float4 gb = *reinterpret_cast<const float4*>(Yb + (size_t)arg * 8);
            const float gw = gb.z - gb.x + 1.f;
            const float gh = gb.w - gb.y + 1.f;
            const float gx = gb.x + 0.5f * gw;
            const float gy = gb.y + 0.5f * gh;
            const float axc = a0 + 0.5f * aw;
            const float ayc = a1 + 0.5f * ah;
            const float t0 = (gx - axc) / aw;
            const float t1 = (gy - ayc) / ah;
            const float t2 = logf(gw / aw);
            const float t3 = logf(gh / ah);
            const float4 r = *reinterpret_cast<const float4*>(
                pred_reg + 4 * ((size_t)b * A + a));
            lr = smooth_l1(r.x - t0) + smooth_l1(r.y - t1)
               + smooth_l1(r.z - t2) + smooth_l1(r.w - t3);
        }
    }

    // wave64 reduction
    for (int off = 32; off > 0; off >>= 1) {
        lc += __shfl_down(lc, off);
        lr += __shfl_down(lr, off);
        fg += __shfl_down(fg, off);
    }

    __shared__ float s_lc[4], s_lr[4];
    __shared__ int s_np[4];
    const int wid = threadIdx.x >> 6;
    const int lane = threadIdx.x & 63;
    if (lane == 0) { s_lc[wid] = lc; s_lr[wid] = lr; s_np[wid] = fg; }
    __syncthreads();
    if (threadIdx.x == 0) {
        const float tlc = s_lc[0] + s_lc[1] + s_lc[2] + s_lc[3];
        const float tlr = s_lr[0] + s_lr[1] + s_lr[2] + s_lr[3];
        const int   tnp = s_np[0] + s_np[1] + s_np[2] + s_np[3];
        __hip_atomic_fetch_add(&ws[0], (double)tlc, __ATOMIC_RELAXED, __HIP_MEMORY_SCOPE_AGENT);
        __hip_atomic_fetch_add(&ws[1], (double)tlr, __ATOMIC_RELAXED, __HIP_MEMORY_SCOPE_AGENT);
        __hip_atomic_fetch_add(&ws[2], (double)tnp, __ATOMIC_RELAXED, __HIP_MEMORY_SCOPE_AGENT);
    }
}

__global__ void finalize_kernel(const double* __restrict__ ws, float* __restrict__ out) {
    if (threadIdx.x == 0 && blockIdx.x == 0) {
        const double npos = ws[2] < 1.0 ? 1.0 : ws[2];
        const double norm = 0.9 * 100.0 + 0.1 * npos;
        out[0] = (float)(ws[0] / norm);
        out[1] = (float)(ws[1] / norm);
    }
}

extern "C" void kernel_launch(void* const* d_in, const int* in_sizes, int n_in,
                              void* d_out, int out_size, void* d_ws, size_t ws_size,
                              hipStream_t stream) {
    const float* pred_cls = (const float*)d_in[0];
    const float* pred_reg = (const float*)d_in[1];
    const float* anchors  = (const float*)d_in[2];
    const float* gt_boxes = (const float*)d_in[3];
    const float* im_info  = (const float*)d_in[4];

    const int A = in_sizes[2] / 4;
    const int B = in_sizes[4] / 6;
    const int G = in_sizes[3] / (B * 5);
    const int Gp = (G + 3) & ~3;                 // pad to tile multiple
    const int ntmax = Gp / 4;

    double* ws = (double*)d_ws;
    float* X = (float*)((char*)d_ws + WS_X_BYTE_OFF);
    const size_t xbytes = (size_t)B * (ntmax + 1) * 20 * sizeof(float);
    float* Y = (float*)((char*)d_ws + WS_X_BYTE_OFF + ((xbytes + 255) & ~(size_t)255));

    const int total_slots = B * (Gp + 4);
    prep_gt_kernel<<<(total_slots + 255) / 256, 256, 0, stream>>>(
        gt_boxes, im_info, X, Y, ws, G, Gp, ntmax, B);

    dim3 grid((A + 255) / 256, B);
    retina_loss_kernel<<<grid, 256, 0, stream>>>(
        pred_cls, pred_reg, anchors, im_info, X, Y, A, ntmax, Gp, ws);
    finalize_kernel<<<1, 1, 0, stream>>>(ws, (float*)d_out);
}

// Round 7
// 89.624 us; speedup vs baseline: 1.0337x; 1.0337x over previous
//
#include <hip/hip_runtime.h>
#include <math.h>

// CrowdDet RetinaNet loss constants
#define POS_T 0.5f
#define NEG_T 0.4f
#define F_ALPHA 0.25f
#define SL1_BETA 0.1f
#define SENT 3.0e8f

// d_ws layout:
//   [0,24)      : 3 doubles (loss_cls, loss_reg, num_pos)
//   [512, +XB)  : X — SGPR-chunk SoA tiles. Per batch: NC chunks x 40 floats:
//                 chunk c = {G0[8], G1[8], G2P[8], G3P[8], AREA[8]}
//                 (G2P/G3P carry the pre-added +1; sentinels never win argmax)
//   [Yoff, ...) : Y — epilogue records, stride 8 floats per gt:
//                 {g0, g1, g2, g3, cls, 0, 0, 0}
#define WS_X_BYTE_OFF 512

typedef __attribute__((ext_vector_type(8))) int i8x;

__device__ __forceinline__ float smooth_l1(float d) {
    d = fabsf(d);
    return d < SL1_BETA ? 0.5f * d * d / SL1_BETA : d - SL1_BETA;
}

__global__ void prep_gt_kernel(const float* __restrict__ gt,
                               const float* __restrict__ im_info,
                               float* __restrict__ X, float* __restrict__ Y,
                               double* __restrict__ ws,
                               int G, int Gp, int NC, int B) {
#pragma clang fp contract(off)
    const int i = blockIdx.x * 256 + threadIdx.x;
    if (i < 3) ws[i] = 0.0;
    const int total = B * Gp;
    if (i >= total) return;
    const int b = i / Gp, j = i - b * Gp;
    const int nv = (int)im_info[b * 6 + 5];

    float g0, g1, g2, g3, cls, area;
    if (j < nv) {
        const float* s = gt + ((size_t)b * G + j) * 5;
        g0 = s[0]; g1 = s[1]; g2 = s[2]; g3 = s[3]; cls = s[4];
        area = (g2 - g0 + 1.f) * (g3 - g1 + 1.f);   // exact ref op order
    } else {
        // Sentinel far-away box: inter = 0 with any real anchor; once a real
        // gt is in (bi >= 0), 0*bS > bi*S never holds -> can't win argmax.
        g0 = SENT; g1 = SENT; g2 = SENT + 1.f; g3 = SENT + 1.f;
        cls = 0.f; area = 4.f;
    }

    // SoA chunk store (5 scalar writes, tiny kernel)
    float* xc = X + (size_t)b * NC * 40 + (size_t)(j >> 3) * 40;
    const int l = j & 7;
    xc[0 * 8 + l] = g0;
    xc[1 * 8 + l] = g1;
    xc[2 * 8 + l] = g2 + 1.f;    // pre-added +1 for iw/ih
    xc[3 * 8 + l] = g3 + 1.f;
    xc[4 * 8 + l] = area;

    float* y = Y + ((size_t)b * Gp + j) * 8;
    reinterpret_cast<float4*>(y)[0] = make_float4(g0, g1, g2, g3);
    y[4] = cls;
}

// 1 anchor/thread. GT chunks fetched to SGPRs via explicit s_load_dwordx8;
// inner loop is pure VALU with one SGPR operand per instruction.
__global__ __launch_bounds__(256) void retina_loss_kernel(
    const float* __restrict__ pred_cls,   // [B,A,1]
    const float* __restrict__ pred_reg,   // [B,A,4]
    const float* __restrict__ anchors,    // [A,4]
    const float* __restrict__ im_info,    // [B,6]
    const float* __restrict__ X,          // SoA chunks
    const float* __restrict__ Y,          // epilogue records
    int A, int NC, int Gp,
    double* __restrict__ ws)
{
#pragma clang fp contract(off)
    const int b = blockIdx.y;
    const int a_raw = blockIdx.x * 256 + threadIdx.x;
    const bool live = a_raw < A;
    const int a = min(a_raw, A - 1);      // clamp: uniform control flow
    const int nvalid = __builtin_amdgcn_readfirstlane((int)im_info[b * 6 + 5]);
    const int nch = (nvalid + 7) >> 3;    // sentinels cover the tail
    const float* __restrict__ Xb = X + (size_t)b * NC * 40;
    const float* __restrict__ Yb = Y + (size_t)b * Gp * 8;

    const float4 anc = *reinterpret_cast<const float4*>(anchors + 4 * (size_t)a);
    const float a0 = anc.x, a1 = anc.y;
    const float aw = anc.z - anc.x + 1.f;
    const float ah = anc.w - anc.y + 1.f;
    const float area_a = aw * ah;
    const float a2p = anc.z + 1.f;        // +1 pre-added (monotone rounding:
    const float a3p = anc.w + 1.f;        //  commutes with min; inter only
                                          //  feeds ordering/thresholds)

    // Division-free IoU argmax: iou = inter/(S-inter) monotone in inter/S =>
    // iou_i > iou_j  <=>  inter_i*S_j > inter_j*S_i (S>0). Init (-1,1) makes
    // the first gt always win; strict > == first-max (jnp.argmax tie-break).
    float bi = -1.f, bS = 1.f;
    int arg = 0;

    for (int c = 0; c < nch; ++c) {
        const float* cp = Xb + (size_t)c * 40;
        i8x r0, r1, r2, r3, r4;
        // Whole chunk -> 40 SGPRs. waitcnt inside the block: outputs are
        // defined by the asm, so no use can be scheduled before the wait.
        asm volatile(
            "s_load_dwordx8 %0, %5, 0x0\n\t"
            "s_load_dwordx8 %1, %5, 0x20\n\t"
            "s_load_dwordx8 %2, %5, 0x40\n\t"
            "s_load_dwordx8 %3, %5, 0x60\n\t"
            "s_load_dwordx8 %4, %5, 0x80\n\t"
            "s_waitcnt lgkmcnt(0)"
            : "=s"(r0), "=s"(r1), "=s"(r2), "=s"(r3), "=s"(r4)
            : "s"(cp));
        const int cb = c << 3;            // uniform -> SALU
        #pragma unroll
        for (int j = 0; j < 8; ++j) {
            const float g0  = __int_as_float(r0[j]);
            const float g1  = __int_as_float(r1[j]);
            const float g2p = __int_as_float(r2[j]);
            const float g3p = __int_as_float(r3[j]);
            const float sg  = __int_as_float(r4[j]);
            const float iw = fminf(a2p, g2p) - fmaxf(a0, g0);
            const float ih = fminf(a3p, g3p) - fmaxf(a1, g1);
            const float inter = fmaxf(iw, 0.f) * fmaxf(ih, 0.f);
            const float S = area_a + sg;
            const bool upd = inter * bS > bi * S;
            bi  = upd ? inter    : bi;
            bS  = upd ? S        : bS;
            arg = upd ? (cb + j) : arg;   // cb+j uniform -> s_add + cndmask
        }
    }

    float lc = 0.f, lr = 0.f;
    int fg = 0;

    if (live) {
        // ONE division, exact ref expression: inter/((area_a+area_g)-inter)
        const float max_ov = bi / (bS - bi);

        float label = 0.f;
        bool valid = true;
        if (max_ov >= POS_T) {
            label = Yb[(size_t)arg * 8 + 4];
        } else if (max_ov >= NEG_T) {
            valid = false;                 // ignore band
        }
        fg = (label > 0.f) ? 1 : 0;

        if (valid) {
            const float x = pred_cls[(size_t)b * A + a];
            const float p = 1.f / (1.f + expf(-x));
            const float l1p = log1pf(expf(-fabsf(x)));
            const float log_p  = fminf(x, 0.f) - l1p;    // log_sigmoid(x)
            const float log_np = fminf(-x, 0.f) - l1p;   // log_sigmoid(-x)
            const float pos = (label == 1.f) ? 1.f : 0.f;
            const float omp = 1.f - p;
            lc = -(F_ALPHA * pos * (omp * omp) * log_p
                   + (1.f - F_ALPHA) * (1.f - pos) * (p * p) * log_np);
        }

        if (fg) {
            const float4 gb = *reinterpret_cast<const float4*>(Yb + (size_t)arg * 8);
            const float gw = gb.z - gb.x + 1.f;
            const float gh = gb.w - gb.y + 1.f;
            const float gx = gb.x + 0.5f * gw;
            const float gy = gb.y + 0.5f * gh;
            const float axc = a0 + 0.5f * aw;
            const float ayc = a1 + 0.5f * ah;
            const float t0 = (gx - axc) / aw;
            const float t1 = (gy - ayc) / ah;
            const float t2 = logf(gw / aw);
            const float t3 = logf(gh / ah);
            const float4 r = *reinterpret_cast<const float4*>(
                pred_reg + 4 * ((size_t)b * A + a));
            lr = smooth_l1(r.x - t0) + smooth_l1(r.y - t1)
               + smooth_l1(r.z - t2) + smooth_l1(r.w - t3);
        }
    }

    // wave64 reduction
    for (int off = 32; off > 0; off >>= 1) {
        lc += __shfl_down(lc, off);
        lr += __shfl_down(lr, off);
        fg += __shfl_down(fg, off);
    }

    __shared__ float s_lc[4], s_lr[4];
    __shared__ int s_np[4];
    const int wid = threadIdx.x >> 6;
    const int lane = threadIdx.x & 63;
    if (lane == 0) { s_lc[wid] = lc; s_lr[wid] = lr; s_np[wid] = fg; }
    __syncthreads();
    if (threadIdx.x == 0) {
        const float tlc = s_lc[0] + s_lc[1] + s_lc[2] + s_lc[3];
        const float tlr = s_lr[0] + s_lr[1] + s_lr[2] + s_lr[3];
        const int   tnp = s_np[0] + s_np[1] + s_np[2] + s_np[3];
        __hip_atomic_fetch_add(&ws[0], (double)tlc, __ATOMIC_RELAXED, __HIP_MEMORY_SCOPE_AGENT);
        __hip_atomic_fetch_add(&ws[1], (double)tlr, __ATOMIC_RELAXED, __HIP_MEMORY_SCOPE_AGENT);
        __hip_atomic_fetch_add(&ws[2], (double)tnp, __ATOMIC_RELAXED, __HIP_MEMORY_SCOPE_AGENT);
    }
}

__global__ void finalize_kernel(const double* __restrict__ ws, float* __restrict__ out) {
    if (threadIdx.x == 0 && blockIdx.x == 0) {
        const double npos = ws[2] < 1.0 ? 1.0 : ws[2];
        const double norm = 0.9 * 100.0 + 0.1 * npos;
        out[0] = (float)(ws[0] / norm);
        out[1] = (float)(ws[1] / norm);
    }
}

extern "C" void kernel_launch(void* const* d_in, const int* in_sizes, int n_in,
                              void* d_out, int out_size, void* d_ws, size_t ws_size,
                              hipStream_t stream) {
    const float* pred_cls = (const float*)d_in[0];
    const float* pred_reg = (const float*)d_in[1];
    const float* anchors  = (const float*)d_in[2];
    const float* gt_boxes = (const float*)d_in[3];
    const float* im_info  = (const float*)d_in[4];

    const int A = in_sizes[2] / 4;
    const int B = in_sizes[4] / 6;
    const int G = in_sizes[3] / (B * 5);
    const int NC = (G + 7) / 8;                  // 8-gt chunks
    const int Gp = NC * 8;                       // sentinel-padded gt count

    double* ws = (double*)d_ws;
    float* X = (float*)((char*)d_ws + WS_X_BYTE_OFF);
    const size_t xbytes = (size_t)B * NC * 40 * sizeof(float);
    float* Y = (float*)((char*)d_ws + WS_X_BYTE_OFF + ((xbytes + 255) & ~(size_t)255));

    const int total_slots = B * Gp;
    prep_gt_kernel<<<(total_slots + 255) / 256, 256, 0, stream>>>(
        gt_boxes, im_info, X, Y, ws, G, Gp, NC, B);

    dim3 grid((A + 255) / 256, B);
    retina_loss_kernel<<<grid, 256, 0, stream>>>(
        pred_cls, pred_reg, anchors, im_info, X, Y, A, NC, Gp, ws);
    finalize_kernel<<<1, 1, 0, stream>>>(ws, (float*)d_out);
}